// Round 5
// baseline (313.902 us; speedup 1.0000x reference)
//
#include <hip/hip_runtime.h>
#include <cstdint>
#include <cstddef>

// Problem constants
constexpr int DD = 1024;        // D
constexpr int TT = 4096;        // T
constexpr int BB = 4;           // B
constexpr int MM = BB * TT;     // 16384 rows

typedef __bf16 bf16x8 __attribute__((ext_vector_type(8)));
typedef float  f32x4  __attribute__((ext_vector_type(4)));

__device__ __forceinline__ unsigned short f2bf(float f) {
  union { float f; uint32_t u; } c; c.f = f;
  uint32_t r = (c.u + 0x7FFFu + ((c.u >> 16) & 1u)) >> 16;
  return (unsigned short)r;
}

__device__ __forceinline__ float fast_rcp(float x) {
  return __builtin_amdgcn_rcpf(x);
}

// async global->LDS 16B per lane; lds_dst must be wave-uniform (HW adds lane*16)
__device__ __forceinline__ void async_ld16(const unsigned short* g, unsigned short* lds_dst) {
  __builtin_amdgcn_global_load_lds(
      (const __attribute__((address_space(1))) void*)g,
      (__attribute__((address_space(3))) void*)lds_dst,
      16, 0, 0);
}

#define VWAIT(n) asm volatile("s_waitcnt vmcnt(" #n ")" ::: "memory")
#define LWAIT0() asm volatile("s_waitcnt lgkmcnt(0)" ::: "memory")
#define SB()     __builtin_amdgcn_sched_barrier(0)

// R1-verified swizzle (measured 0 bank conflicts on this 64B-row layout):
// XOR byte bit-9 into bit-5 within each 1024B plane (16 rows x 64B). Involution.
__device__ __forceinline__ int swzb(int b) { return b ^ (((b >> 9) & 1) << 5); }

// ---------------------------------------------------------------------------
// Merged prep: blocks [0,1024) fold time-mix into weights (wave per row) and
// accumulate bias dots; blocks [1024, 1024+16384) convert x to bf16 and emit
// x[:, T-1, :].
__global__ void prep_all(const float* __restrict__ Wk, const float* __restrict__ Wv,
                         const float* __restrict__ Wr, const float* __restrict__ Wo,
                         const float* __restrict__ tmk, const float* __restrict__ tmv,
                         const float* __restrict__ tmr,
                         const float* __restrict__ last_x,
                         const float4* __restrict__ x,
                         unsigned short* __restrict__ wz,   // [3][1024][1024] bf16
                         unsigned short* __restrict__ wo,   // [1024][1024] bf16
                         float* __restrict__ bias,          // [3][1024]
                         ushort4* __restrict__ xb,          // [16384][1024] bf16
                         float4* __restrict__ out_xlast) {
  if (blockIdx.x < 1024) {
    int w = (blockIdx.x * 256 + threadIdx.x) >> 6;   // 0..4095
    int lane = threadIdx.x & 63;
    int z = w >> 10;           // 0..3
    int e = w & (DD - 1);
    const float* W  = (z == 0) ? Wk  : (z == 1) ? Wv  : (z == 2) ? Wr : Wo;
    const float* tm = (z == 0) ? tmk : (z == 1) ? tmv : tmr;
    unsigned short* dst = (z < 3) ? (wz + (size_t)z * DD * DD + (size_t)e * DD)
                                  : (wo + (size_t)e * DD);
    float s = 0.f;
#pragma unroll
    for (int j = 0; j < 4; ++j) {
      int d = j * 256 + lane * 4;
      float4 wv4 = *(const float4*)(W + (size_t)e * DD + d);
      if (z < 3) {
        float4 t4 = *(const float4*)(tm + d);
        float4 l4 = *(const float4*)(last_x + d);
        s += l4.x * (1.f - t4.x) * wv4.x + l4.y * (1.f - t4.y) * wv4.y +
             l4.z * (1.f - t4.z) * wv4.z + l4.w * (1.f - t4.w) * wv4.w;
        wv4.x *= t4.x; wv4.y *= t4.y; wv4.z *= t4.z; wv4.w *= t4.w;
      }
      ushort4 o;
      o.x = f2bf(wv4.x); o.y = f2bf(wv4.y); o.z = f2bf(wv4.z); o.w = f2bf(wv4.w);
      *(ushort4*)(dst + d) = o;
    }
    if (z < 3) {
      for (int off = 32; off; off >>= 1) s += __shfl_down(s, off, 64);
      if (lane == 0) bias[z * DD + e] = s;
    }
  } else {
    int i = (blockIdx.x - 1024) * 256 + threadIdx.x;  // < MM*DD/4
    float4 v = x[i];
    ushort4 o;
    o.x = f2bf(v.x); o.y = f2bf(v.y); o.z = f2bf(v.z); o.w = f2bf(v.w);
    xb[i] = o;
    int m = i >> 8;                                    // 256 float4 per row
    if ((m & (TT - 1)) == (TT - 1)) {
      int b = m >> 12;
      out_xlast[b * 256 + (i & 255)] = v;
    }
  }
}

// ---------------------------------------------------------------------------
// Fused GEMM1 + WKV. R0's exact geometry (256 thr, 4 waves, 128m x 64n x 3z,
// same fragment/MFMA body, same epilogue) with ONE structural change:
// 4-slot LDS ring of BK=32 K-slabs + uniform counted vmcnt. Iter t computes
// slot t&3 while tiles t+1..t+3 are in flight; end-of-iter waits vmcnt(10)
// (tile t+1 landed, 2 stage-groups still flying) + lgkmcnt(0) + raw s_barrier
// (no implicit vmcnt(0) drain -> the m233 stage stall is amortized away).
// Plus the R1-verified LDS swizzle (0 conflicts) on both sides.
__global__ __launch_bounds__(256, 2) void gemm_kvr(
    const unsigned short* __restrict__ A,     // [16384][1024] bf16
    const unsigned short* __restrict__ Wz,    // [3][1024][1024] bf16
    const float* __restrict__ bias,           // [3][1024]
    const float* __restrict__ time_first, const float* __restrict__ time_decay,
    const float* __restrict__ last_num, const float* __restrict__ last_den,
    unsigned short* __restrict__ rwkv,        // [16384][1024] bf16
    float* __restrict__ out_num, float* __restrict__ out_den) {
  // Ring: A slot 128x32 (8 KiB), B slot 3x64x32 (12 KiB); x4 = 80 KiB
  __shared__ __align__(1024) unsigned short sA[4][128 * 32];
  __shared__ __align__(1024) unsigned short sB[4][3 * 64 * 32];
  const int tid  = threadIdx.x;
  const int lane = tid & 63;
  const int wave = tid >> 6;    // 0..3

  // XCD-aware remap of (n0, m0). Grid: 16 x 128 = 2048 blocks.
  const int id  = blockIdx.y * gridDim.x + blockIdx.x;   // 0..2047
  const int xcd = id & 7;
  const int s   = id >> 3;                               // 0..255
  const int m0 = (xcd * 16 + (s >> 4)) * 128;            // m-stripe
  const int n0 = (s & 15) * 64;                          // zone-local col base

  const int wm = (wave >> 1) * 64;
  const int wn = (wave & 1) * 32;
  const int fr = lane & 15;
  const int fq = lane >> 4;

  // Fragment ds_read byte offsets (slot-relative, swizzled).
  int phA[4], phB[3][2];
#pragma unroll
  for (int m = 0; m < 4; ++m)
    phA[m] = swzb((wm + m * 16 + fr) * 64 + fq * 16);
#pragma unroll
  for (int z = 0; z < 3; ++z)
#pragma unroll
    for (int n = 0; n < 2; ++n)
      phB[z][n] = swzb(z * 4096 + (wn + n * 16 + fr) * 64 + fq * 16);

  // Staging maps: every thread issues 2 A-loads + 3 B-loads per slot.
  // Linear LDS dest (wave-uniform base + lane*16); per-lane global source is
  // inverse-swizzled (involution) so swizzled ds_reads see the right data.
  size_t aSrc[2]; int aDst[2];
#pragma unroll
  for (int it = 0; it < 2; ++it) {
    int plane = it * 4 + wave;              // 0..7 (A slot = 8 planes)
    aDst[it] = plane * 1024;
    int pb = plane * 1024 + lane * 16;      // physical byte this lane fills
    int lq = swzb(pb);                      // logical byte
    int r = lq >> 6, cb = lq & 63;          // row 0..127, col byte 0..63
    aSrc[it] = (size_t)(m0 + r) * DD + (cb >> 1);
  }
  size_t bSrc[3]; int bDst[3];
#pragma unroll
  for (int j = 0; j < 3; ++j) {
    int base = j * 4096 + wave * 1024;      // z-section j, plane = wave
    bDst[j] = base;
    int pb = base + lane * 16;
    int lq = swzb(pb);
    int r = lq >> 6, cb = lq & 63;          // row 0..191
    int z = r >> 6, zr = r & 63;
    bSrc[j] = (size_t)z * DD * DD + (size_t)(n0 + zr) * DD + (cb >> 1);
  }

  auto stage = [&](int slot, int tile) {
    const int kk = tile * 32;
#pragma unroll
    for (int it = 0; it < 2; ++it)
      async_ld16(A + aSrc[it] + kk, (unsigned short*)((char*)sA[slot] + aDst[it]));
#pragma unroll
    for (int j = 0; j < 3; ++j)
      async_ld16(Wz + bSrc[j] + kk, (unsigned short*)((char*)sB[slot] + bDst[j]));
  };

  f32x4 acc[3][4][2] = {};

  // Prologue: fill slots 0..2 (15 loads); wait slot 0 (10 = 2 groups flying).
  stage(0, 0);
  stage(1, 1);
  stage(2, 2);
  VWAIT(10); SB();
  __builtin_amdgcn_s_barrier();
  SB();

#pragma unroll 1
  for (int t = 0; t < 32; ++t) {
    const int slot = t & 3;
    if (t < 29) stage((t + 3) & 3, t + 3);   // restages slot (t-1)&3: its readers drained last iter
    SB();

    // R0's compute body (compiler-scheduled fine-grained lgkmcnt), BK=32 slab.
    bf16x8 af[4], bfr[3][2];
#pragma unroll
    for (int m = 0; m < 4; ++m)
      af[m] = *(const bf16x8*)((const char*)sA[slot] + phA[m]);
#pragma unroll
    for (int z = 0; z < 3; ++z)
#pragma unroll
      for (int n = 0; n < 2; ++n)
        bfr[z][n] = *(const bf16x8*)((const char*)sB[slot] + phB[z][n]);

#pragma unroll
    for (int mi = 0; mi < 4; ++mi)
#pragma unroll
      for (int z = 0; z < 3; ++z)
#pragma unroll
        for (int ni = 0; ni < 2; ++ni)
          acc[z][mi][ni] = __builtin_amdgcn_mfma_f32_16x16x32_bf16(
              af[mi], bfr[z][ni], acc[z][mi][ni], 0, 0, 0);

    if (t < 31) {
      LWAIT0();                      // all my reads of slot t consumed
      if (t < 29)       VWAIT(10);   // tile t+1 landed; 2 groups stay in flight
      else if (t == 29) VWAIT(5);
      else              VWAIT(0);
      SB();
      __builtin_amdgcn_s_barrier();  // raw barrier: publish slot t+1, no drain
      SB();
    }
  }

  // Epilogue: WKV in-register. C/D layout: col = lane&15, row = (lane>>4)*4 + reg.
  const int crow = fq * 4;
  const int ccol = fr;
#pragma unroll
  for (int ni = 0; ni < 2; ++ni) {
    int gnz = n0 + wn + ni * 16 + ccol;   // channel d
    float bk = bias[gnz], bv = bias[DD + gnz], br = bias[2 * DD + gnz];
    float tf = time_first[gnz];
    float ln = last_num[gnz], ld = last_den[gnz];
    float dec = __expf(-__expf(time_decay[gnz]));   // hoisted
#pragma unroll
    for (int mi = 0; mi < 4; ++mi) {
#pragma unroll
      for (int r = 0; r < 4; ++r) {
        int gm = m0 + wm + mi * 16 + crow + r;
        float kk = acc[0][mi][ni][r] + bk;
        float vv = acc[1][mi][ni][r] + bv;
        float rr = acc[2][mi][ni][r] + br;
        float efk = __expf(tf + kk);
        float wkv = (ln + efk * vv) * fast_rcp(ld + efk);
        float sr  = fast_rcp(1.0f + __expf(-rr));
        rwkv[(size_t)gm * DD + gnz] = f2bf(sr * wkv);
        if ((gm & (TT - 1)) == (TT - 1)) {
          int b = gm >> 12;
          float ek = __expf(kk);
          out_num[b * DD + gnz] = dec * ln + ek * vv;
          out_den[b * DD + gnz] = dec * ld + ek;
        }
      }
    }
  }
}

// ---------------------------------------------------------------------------
// GEMM2: C[M,N] = A[M,K] @ B[N,K]^T, fp32 out. Same 4-slot counted-vmcnt ring
// (4 loads/slot -> vmcnt(8)) + swizzle, on the R0 128x128 geometry.
__global__ void gemm_bt128(const unsigned short* __restrict__ A,
                           const unsigned short* __restrict__ Bw,
                           float* __restrict__ Cf,
                           int M, int N, int K) {
  __shared__ __align__(1024) unsigned short sA[4][128 * 32];   // 4 x 8 KiB
  __shared__ __align__(1024) unsigned short sB[4][128 * 32];   // 4 x 8 KiB
  const int tid  = threadIdx.x;
  const int lane = tid & 63;
  const int wave = tid >> 6;

  // XCD-aware remap: m-stripes partitioned across XCDs, n fastest.
  const int nBlocks = N >> 7;
  const int mBlocks = M >> 7;
  const int id  = blockIdx.y * gridDim.x + blockIdx.x;
  const int xcd = id & 7;
  const int s   = id >> 3;
  const int mPer = mBlocks >> 3;           // m-stripes per XCD (M=16384 -> 16)
  const int m0 = (xcd * mPer + s / nBlocks) * 128;
  const int n0 = (s % nBlocks) * 128;

  const int wm = (wave >> 1) * 64;
  const int wn = (wave & 1) * 64;
  const int fr = lane & 15;
  const int fq = lane >> 4;

  int phA[4], phB[4];
#pragma unroll
  for (int i = 0; i < 4; ++i) {
    phA[i] = swzb((wm + i * 16 + fr) * 64 + fq * 16);
    phB[i] = swzb((wn + i * 16 + fr) * 64 + fq * 16);
  }

  // Staging: 2 A + 2 B loads per thread per slot.
  size_t aSrc[2], bSrc[2]; int dstO[2];
#pragma unroll
  for (int it = 0; it < 2; ++it) {
    int plane = it * 4 + wave;
    dstO[it] = plane * 1024;
    int pb = plane * 1024 + lane * 16;
    int lq = swzb(pb);
    int r = lq >> 6, cb = lq & 63;
    aSrc[it] = (size_t)(m0 + r) * K + (cb >> 1);
    bSrc[it] = (size_t)(n0 + r) * K + (cb >> 1);
  }

  auto stage = [&](int slot, int tile) {
    const int kk = tile * 32;
#pragma unroll
    for (int it = 0; it < 2; ++it)
      async_ld16(A + aSrc[it] + kk, (unsigned short*)((char*)sA[slot] + dstO[it]));
#pragma unroll
    for (int it = 0; it < 2; ++it)
      async_ld16(Bw + bSrc[it] + kk, (unsigned short*)((char*)sB[slot] + dstO[it]));
  };

  f32x4 acc[4][4] = {};
  const int nt = K >> 5;   // 32

  stage(0, 0);
  stage(1, 1);
  stage(2, 2);
  VWAIT(8); SB();
  __builtin_amdgcn_s_barrier();
  SB();

#pragma unroll 1
  for (int t = 0; t < nt; ++t) {
    const int slot = t & 3;
    if (t + 3 < nt) stage((t + 3) & 3, t + 3);
    SB();

    bf16x8 af[4], bfr[4];
#pragma unroll
    for (int i = 0; i < 4; ++i) {
      af[i]  = *(const bf16x8*)((const char*)sA[slot] + phA[i]);
      bfr[i] = *(const bf16x8*)((const char*)sB[slot] + phB[i]);
    }
#pragma unroll
    for (int mi = 0; mi < 4; ++mi)
#pragma unroll
      for (int ni = 0; ni < 4; ++ni)
        acc[mi][ni] = __builtin_amdgcn_mfma_f32_16x16x32_bf16(af[mi], bfr[ni], acc[mi][ni], 0, 0, 0);

    if (t < nt - 1) {
      LWAIT0();
      if (t < nt - 3)       VWAIT(8);
      else if (t == nt - 3) VWAIT(4);
      else                  VWAIT(0);
      SB();
      __builtin_amdgcn_s_barrier();
      SB();
    }
  }

  const int crow = fq * 4;
  const int ccol = fr;
#pragma unroll
  for (int mi = 0; mi < 4; ++mi) {
#pragma unroll
    for (int ni = 0; ni < 4; ++ni) {
      int gn = n0 + wn + ni * 16 + ccol;
#pragma unroll
      for (int r = 0; r < 4; ++r) {
        int gm = m0 + wm + mi * 16 + crow + r;
        Cf[(size_t)gm * N + gn] = acc[mi][ni][r];
      }
    }
  }
}

// ---------------------------------------------------------------------------
extern "C" void kernel_launch(void* const* d_in, const int* in_sizes, int n_in,
                              void* d_out, int out_size, void* d_ws, size_t ws_size,
                              hipStream_t stream) {
  const float* x          = (const float*)d_in[0];
  const float* last_x     = (const float*)d_in[1];
  const float* last_num   = (const float*)d_in[2];
  const float* last_den   = (const float*)d_in[3];
  const float* time_decay = (const float*)d_in[4];
  const float* time_first = (const float*)d_in[5];
  const float* tmk        = (const float*)d_in[6];
  const float* tmv        = (const float*)d_in[7];
  const float* tmr        = (const float*)d_in[8];
  const float* Wk         = (const float*)d_in[9];
  const float* Wv         = (const float*)d_in[10];
  const float* Wr         = (const float*)d_in[11];
  const float* Wo         = (const float*)d_in[12];

  float* out       = (float*)d_out;                  // [MM][DD]
  float* out_xlast = out + (size_t)MM * DD;          // [BB][DD]
  float* out_num   = out_xlast + BB * DD;            // [BB][DD]
  float* out_den   = out_num + BB * DD;              // [BB][DD]

  char* ws = (char*)d_ws;
  unsigned short* xb   = (unsigned short*)ws;                 // 33,554,432 B
  unsigned short* wz   = (unsigned short*)(ws + 33554432);    //  6,291,456 B
  unsigned short* wo   = (unsigned short*)(ws + 39845888);    //  2,097,152 B
  float*          bias = (float*)(ws + 41943040);             //     12,288 B
  unsigned short* rwkv = (unsigned short*)(ws + 41955328);    // 33,554,432 B (no alias with xb)

  prep_all<<<1024 + MM * DD / 4 / 256, 256, 0, stream>>>(
      Wk, Wv, Wr, Wo, tmk, tmv, tmr, last_x, (const float4*)x,
      wz, wo, bias, (ushort4*)xb, (float4*)out_xlast);

  // Fused: kvr GEMM + WKV -> rwkv [16384, 1024], plus num/den state rows
  gemm_kvr<<<dim3(DD / 64, MM / 128), 256, 0, stream>>>(
      xb, wz, bias, time_first, time_decay, last_num, last_den,
      rwkv, out_num, out_den);

  // out = rwkv @ wo^T : [16384, 1024]
  gemm_bt128<<<dim3(DD / 128, MM / 128), 256, 0, stream>>>(
      rwkv, wo, out, MM, DD, DD);
}

// Round 7
// 293.194 us; speedup vs baseline: 1.0706x; 1.0706x over previous
//
#include <hip/hip_runtime.h>
#include <cstdint>
#include <cstddef>

// Problem constants
constexpr int DD = 1024;        // D
constexpr int TT = 4096;        // T
constexpr int BB = 4;           // B
constexpr int MM = BB * TT;     // 16384 rows

typedef __bf16 bf16x8 __attribute__((ext_vector_type(8)));
typedef float  f32x4  __attribute__((ext_vector_type(4)));

__device__ __forceinline__ unsigned short f2bf(float f) {
  union { float f; uint32_t u; } c; c.f = f;
  uint32_t r = (c.u + 0x7FFFu + ((c.u >> 16) & 1u)) >> 16;
  return (unsigned short)r;
}

__device__ __forceinline__ float fast_rcp(float x) {
  return __builtin_amdgcn_rcpf(x);
}

// async global->LDS 16B per lane; lds_dst must be wave-uniform (HW adds lane*16)
__device__ __forceinline__ void async_ld16(const unsigned short* g, unsigned short* lds_dst) {
  __builtin_amdgcn_global_load_lds(
      (const __attribute__((address_space(1))) void*)g,
      (__attribute__((address_space(3))) void*)lds_dst,
      16, 0, 0);
}

#define VWAIT(n) asm volatile("s_waitcnt vmcnt(" #n ")" ::: "memory")
#define LWAIT0() asm volatile("s_waitcnt lgkmcnt(0)" ::: "memory")
#define SB()     __builtin_amdgcn_sched_barrier(0)

// Verified swizzle (R1/R5: measured 0 bank conflicts on 64B-row layout):
// XOR byte bit-9 into bit-5 within each 1024B plane (16 rows x 64B). Involution.
__device__ __forceinline__ int swzb(int b) { return b ^ (((b >> 9) & 1) << 5); }

// ---------------------------------------------------------------------------
// Merged prep: blocks [0,1024) fold time-mix into weights (wave per row) and
// accumulate bias dots; blocks [1024, 1024+16384) convert x to bf16 and emit
// x[:, T-1, :].
__global__ void prep_all(const float* __restrict__ Wk, const float* __restrict__ Wv,
                         const float* __restrict__ Wr, const float* __restrict__ Wo,
                         const float* __restrict__ tmk, const float* __restrict__ tmv,
                         const float* __restrict__ tmr,
                         const float* __restrict__ last_x,
                         const float4* __restrict__ x,
                         unsigned short* __restrict__ wz,   // [3][1024][1024] bf16
                         unsigned short* __restrict__ wo,   // [1024][1024] bf16
                         float* __restrict__ bias,          // [3][1024]
                         ushort4* __restrict__ xb,          // [16384][1024] bf16
                         float4* __restrict__ out_xlast) {
  if (blockIdx.x < 1024) {
    int w = (blockIdx.x * 256 + threadIdx.x) >> 6;   // 0..4095
    int lane = threadIdx.x & 63;
    int z = w >> 10;           // 0..3
    int e = w & (DD - 1);
    const float* W  = (z == 0) ? Wk  : (z == 1) ? Wv  : (z == 2) ? Wr : Wo;
    const float* tm = (z == 0) ? tmk : (z == 1) ? tmv : tmr;
    unsigned short* dst = (z < 3) ? (wz + (size_t)z * DD * DD + (size_t)e * DD)
                                  : (wo + (size_t)e * DD);
    float s = 0.f;
#pragma unroll
    for (int j = 0; j < 4; ++j) {
      int d = j * 256 + lane * 4;
      float4 wv4 = *(const float4*)(W + (size_t)e * DD + d);
      if (z < 3) {
        float4 t4 = *(const float4*)(tm + d);
        float4 l4 = *(const float4*)(last_x + d);
        s += l4.x * (1.f - t4.x) * wv4.x + l4.y * (1.f - t4.y) * wv4.y +
             l4.z * (1.f - t4.z) * wv4.z + l4.w * (1.f - t4.w) * wv4.w;
        wv4.x *= t4.x; wv4.y *= t4.y; wv4.z *= t4.z; wv4.w *= t4.w;
      }
      ushort4 o;
      o.x = f2bf(wv4.x); o.y = f2bf(wv4.y); o.z = f2bf(wv4.z); o.w = f2bf(wv4.w);
      *(ushort4*)(dst + d) = o;
    }
    if (z < 3) {
      for (int off = 32; off; off >>= 1) s += __shfl_down(s, off, 64);
      if (lane == 0) bias[z * DD + e] = s;
    }
  } else {
    int i = (blockIdx.x - 1024) * 256 + threadIdx.x;  // < MM*DD/4
    float4 v = x[i];
    ushort4 o;
    o.x = f2bf(v.x); o.y = f2bf(v.y); o.z = f2bf(v.z); o.w = f2bf(v.w);
    xb[i] = o;
    int m = i >> 8;                                    // 256 float4 per row
    if ((m & (TT - 1)) == (TT - 1)) {
      int b = m >> 12;
      out_xlast[b * 256 + (i & 255)] = v;
    }
  }
}

// ---------------------------------------------------------------------------
// Fused GEMM1 + WKV — byte-exact R0 (119.6us verified): two-panel BK=64,
// 16x16x32 MFMA, linear LDS, XCD-locality swizzle.
__global__ __launch_bounds__(256, 2) void gemm_kvr(
    const unsigned short* __restrict__ A,     // [16384][1024] bf16
    const unsigned short* __restrict__ Wz,    // [3][1024][1024] bf16
    const float* __restrict__ bias,           // [3][1024]
    const float* __restrict__ time_first, const float* __restrict__ time_decay,
    const float* __restrict__ last_num, const float* __restrict__ last_den,
    unsigned short* __restrict__ rwkv,        // [16384][1024] bf16
    float* __restrict__ out_num, float* __restrict__ out_den) {
  __shared__ unsigned short lA[2][128 * 32];
  __shared__ unsigned short lB[2][3][64 * 32];
  const int tid  = threadIdx.x;
  const int lane = tid & 63;
  const int wave = tid >> 6;

  const int id  = blockIdx.y * gridDim.x + blockIdx.x;   // 0..2047
  const int xcd = id & 7;
  const int s   = id >> 3;                               // 0..255
  const int m0 = (xcd * 16 + (s >> 4)) * 128;            // m-stripe
  const int n0 = (s & 15) * 64;                          // zone-local col base

  const int wm = (wave >> 1) * 64;
  const int wn = (wave & 1) * 32;

  f32x4 acc[3][4][2] = {};

  const int fr_row = lane & 15;
  const int fr_kb  = (lane >> 4) * 16;   // byte offset within row (8 bf16)
  const int srow = tid >> 2;             // staging row (0..63)
  const int scol = (tid & 3) * 8;        // staging col (bf16 elems)

  for (int k0 = 0; k0 < DD; k0 += 64) {
    __syncthreads();
#pragma unroll
    for (int h = 0; h < 2; ++h) {
      int kk = k0 + h * 32;
#pragma unroll
      for (int it = 0; it < 2; ++it) {
        int cc  = it * 256 + tid;
        int row = cc >> 2;
        async_ld16(A + (size_t)(m0 + row) * DD + (kk + scol),
                   lA[h] + (size_t)(it * 256 + wave * 64) * 8);
      }
#pragma unroll
      for (int z = 0; z < 3; ++z) {
        async_ld16(Wz + (size_t)z * DD * DD + (size_t)(n0 + srow) * DD + (kk + scol),
                   lB[h][z] + (size_t)(wave * 64) * 8);
      }
    }
    __syncthreads();

#pragma unroll
    for (int h = 0; h < 2; ++h) {
      bf16x8 af[4], bfr[3][2];
#pragma unroll
      for (int i = 0; i < 4; ++i)
        af[i] = *(const bf16x8*)((const char*)lA[h] + ((wm + i * 16 + fr_row) * 64 + fr_kb));
#pragma unroll
      for (int z = 0; z < 3; ++z)
#pragma unroll
        for (int j = 0; j < 2; ++j)
          bfr[z][j] = *(const bf16x8*)((const char*)lB[h][z] + ((wn + j * 16 + fr_row) * 64 + fr_kb));

#pragma unroll
      for (int mi = 0; mi < 4; ++mi)
#pragma unroll
        for (int z = 0; z < 3; ++z)
#pragma unroll
          for (int ni = 0; ni < 2; ++ni)
            acc[z][mi][ni] = __builtin_amdgcn_mfma_f32_16x16x32_bf16(
                af[mi], bfr[z][ni], acc[z][mi][ni], 0, 0, 0);
    }
  }

  // Epilogue: WKV in-register. C/D layout: col = lane&15, row = (lane>>4)*4 + reg.
  const int crow = (lane >> 4) * 4;
  const int ccol = lane & 15;
#pragma unroll
  for (int ni = 0; ni < 2; ++ni) {
    int gnz = n0 + wn + ni * 16 + ccol;   // zone-local channel d
    float bk = bias[gnz], bv = bias[DD + gnz], br = bias[2 * DD + gnz];
    float tf = time_first[gnz];
    float ln = last_num[gnz], ld = last_den[gnz];
    float dec = __expf(-__expf(time_decay[gnz]));   // hoisted
#pragma unroll
    for (int mi = 0; mi < 4; ++mi) {
#pragma unroll
      for (int r = 0; r < 4; ++r) {
        int gm = m0 + wm + mi * 16 + crow + r;
        float kk = acc[0][mi][ni][r] + bk;
        float vv = acc[1][mi][ni][r] + bv;
        float rr = acc[2][mi][ni][r] + br;
        float efk = __expf(tf + kk);
        float wkv = (ln + efk * vv) * fast_rcp(ld + efk);
        float sr  = fast_rcp(1.0f + __expf(-rr));
        rwkv[(size_t)gm * DD + gnz] = f2bf(sr * wkv);
        if ((gm & (TT - 1)) == (TT - 1)) {
          int b = gm >> 12;
          float ek = __expf(kk);
          out_num[b * DD + gnz] = dec * ln + ek * vv;
          out_den[b * DD + gnz] = dec * ld + ek;
        }
      }
    }
  }
}

// ---------------------------------------------------------------------------
// GEMM2 rebuilt as the faithful 8-phase 256^2 template (m201 structure):
// ring of 4 K-32 slabs (A 16KiB + B 16KiB each = 128KiB LDS), 8 waves
// (2M x 4N, per-wave 128x64, acc = 32 f32x4), per slab TWO phases of
// {8-or-4 ds_read_b128 | 2 global_load_lds | barrier | lgkmcnt(0)+SB |
// setprio(1) 16 MFMA setprio(0) | barrier}, vmcnt(8) once per slab (never 0
// until tail). Slot (t-1)&3 restaged only after slab t-1's end barrier
// (all readers lgkm-drained before it) -> WAR-safe. Verified swizzle both-sides.
__global__ __launch_bounds__(512, 2) void gemm_bt256(
    const unsigned short* __restrict__ A,
    const unsigned short* __restrict__ Bw,
    float* __restrict__ Cf,
    int M, int N, int K) {
  __shared__ __align__(1024) unsigned short sA[4][256 * 32];   // 4 x 16 KiB
  __shared__ __align__(1024) unsigned short sB[4][256 * 32];   // 4 x 16 KiB
  const int tid  = threadIdx.x;
  const int lane = tid & 63;
  const int wave = tid >> 6;    // 0..7

  // XCD swizzle. Grid (N/256) x (M/256) = 4 x 64 = 256 blocks (1/CU).
  const int id  = blockIdx.y * gridDim.x + blockIdx.x;
  const int xcd = id & 7;
  const int s   = id >> 3;                 // 0..31
  const int m0 = (xcd * 8 + (s >> 2)) * 256;
  const int n0 = (s & 3) * 256;

  const int wm = (wave >> 2) * 128;        // 2 m-wave-groups
  const int wn = (wave & 3) * 64;          // 4 n-wave-groups
  const int fr = lane & 15;
  const int fq = lane >> 4;

  // Fragment ds_read byte offsets (slab-relative, swizzled).
  int phA[8], phB[4];
#pragma unroll
  for (int mi = 0; mi < 8; ++mi)
    phA[mi] = swzb((wm + mi * 16 + fr) * 64 + fq * 16);
#pragma unroll
  for (int ni = 0; ni < 4; ++ni)
    phB[ni] = swzb((wn + ni * 16 + fr) * 64 + fq * 16);

  // Staging: per slab each thread does 2 A-loads (phase 1) + 2 B-loads
  // (phase 2). Linear LDS dest, inverse-swizzled per-lane global source.
  size_t aSrc[2], bSrc[2]; int dPl[2];
#pragma unroll
  for (int u = 0; u < 2; ++u) {
    int plane = u * 8 + wave;               // 0..15
    dPl[u] = plane * 1024;
    int pb = plane * 1024 + lane * 16;      // physical byte this lane fills
    int lq = swzb(pb);                      // logical byte
    int r = lq >> 6, cb = lq & 63;          // row 0..255, col byte
    aSrc[u] = (size_t)(m0 + r) * K + (cb >> 1);
    bSrc[u] = (size_t)(n0 + r) * K + (cb >> 1);
  }
  auto stageA = [&](int slot, int t) {
    const int kk = t * 32;
#pragma unroll
    for (int u = 0; u < 2; ++u)
      async_ld16(A + aSrc[u] + kk, (unsigned short*)((char*)sA[slot] + dPl[u]));
  };
  auto stageB = [&](int slot, int t) {
    const int kk = t * 32;
#pragma unroll
    for (int u = 0; u < 2; ++u)
      async_ld16(Bw + bSrc[u] + kk, (unsigned short*)((char*)sB[slot] + dPl[u]));
  };

  f32x4 acc[8][4] = {};
  const int nt = K >> 5;   // 32 slabs

  // Prologue: slabs 0..2 staged (12 loads/thread); slab 0 landed at vmcnt(8).
  stageA(0, 0); stageB(0, 0);
  stageA(1, 1); stageB(1, 1);
  stageA(2, 2); stageB(2, 2);
  VWAIT(8); SB();
  __builtin_amdgcn_s_barrier();

#pragma unroll 1
  for (int t = 0; t < nt; ++t) {
    const int slot = t & 3;

    // ---- Phase 1: A-frags mi 0-3 + all B-frags (8 ds_read_b128) ----
    bf16x8 af0[4], bf[4];
#pragma unroll
    for (int mi = 0; mi < 4; ++mi)
      af0[mi] = *(const bf16x8*)((const char*)sA[slot] + phA[mi]);
#pragma unroll
    for (int ni = 0; ni < 4; ++ni)
      bf[ni] = *(const bf16x8*)((const char*)sB[slot] + phB[ni]);
    if (t < nt - 3) stageA((t + 3) & 3, t + 3);
    __builtin_amdgcn_s_barrier();
    LWAIT0(); SB();
    __builtin_amdgcn_s_setprio(1);
#pragma unroll
    for (int mi = 0; mi < 4; ++mi)
#pragma unroll
      for (int ni = 0; ni < 4; ++ni)
        acc[mi][ni] = __builtin_amdgcn_mfma_f32_16x16x32_bf16(
            af0[mi], bf[ni], acc[mi][ni], 0, 0, 0);
    __builtin_amdgcn_s_setprio(0);
    __builtin_amdgcn_s_barrier();

    // ---- Phase 2: A-frags mi 4-7 (4 ds_read_b128) ----
    bf16x8 af1[4];
#pragma unroll
    for (int mi = 0; mi < 4; ++mi)
      af1[mi] = *(const bf16x8*)((const char*)sA[slot] + phA[4 + mi]);
    if (t < nt - 3) stageB((t + 3) & 3, t + 3);
    __builtin_amdgcn_s_barrier();
    LWAIT0(); SB();
    __builtin_amdgcn_s_setprio(1);
#pragma unroll
    for (int mi = 0; mi < 4; ++mi)
#pragma unroll
      for (int ni = 0; ni < 4; ++ni)
        acc[4 + mi][ni] = __builtin_amdgcn_mfma_f32_16x16x32_bf16(
            af1[mi], bf[ni], acc[4 + mi][ni], 0, 0, 0);
    __builtin_amdgcn_s_setprio(0);

    // ---- End of slab: counted publish of slot t+1 (never 0 until tail) ----
    if (t < nt - 1) {
      if (t < nt - 3)       VWAIT(8);   // slabs t+2, t+3 in flight
      else if (t == nt - 3) VWAIT(4);   // slab t+3=31 in flight
      else                  VWAIT(0);   // t == nt-2: drain last
      SB();
      __builtin_amdgcn_s_barrier();
    }
  }

  // Epilogue. C/D layout: col = lane&15, row = (lane>>4)*4 + reg.
  const int crow = fq * 4;
  const int ccol = fr;
#pragma unroll
  for (int mi = 0; mi < 8; ++mi) {
#pragma unroll
    for (int ni = 0; ni < 4; ++ni) {
      int gn = n0 + wn + ni * 16 + ccol;
#pragma unroll
      for (int r = 0; r < 4; ++r) {
        int gm = m0 + wm + mi * 16 + crow + r;
        Cf[(size_t)gm * N + gn] = acc[mi][ni][r];
      }
    }
  }
}

// ---------------------------------------------------------------------------
extern "C" void kernel_launch(void* const* d_in, const int* in_sizes, int n_in,
                              void* d_out, int out_size, void* d_ws, size_t ws_size,
                              hipStream_t stream) {
  const float* x          = (const float*)d_in[0];
  const float* last_x     = (const float*)d_in[1];
  const float* last_num   = (const float*)d_in[2];
  const float* last_den   = (const float*)d_in[3];
  const float* time_decay = (const float*)d_in[4];
  const float* time_first = (const float*)d_in[5];
  const float* tmk        = (const float*)d_in[6];
  const float* tmv        = (const float*)d_in[7];
  const float* tmr        = (const float*)d_in[8];
  const float* Wk         = (const float*)d_in[9];
  const float* Wv         = (const float*)d_in[10];
  const float* Wr         = (const float*)d_in[11];
  const float* Wo         = (const float*)d_in[12];

  float* out       = (float*)d_out;                  // [MM][DD]
  float* out_xlast = out + (size_t)MM * DD;          // [BB][DD]
  float* out_num   = out_xlast + BB * DD;            // [BB][DD]
  float* out_den   = out_num + BB * DD;              // [BB][DD]

  char* ws = (char*)d_ws;
  unsigned short* xb   = (unsigned short*)ws;                 // 33,554,432 B
  unsigned short* wz   = (unsigned short*)(ws + 33554432);    //  6,291,456 B
  unsigned short* wo   = (unsigned short*)(ws + 39845888);    //  2,097,152 B
  float*          bias = (float*)(ws + 41943040);             //     12,288 B
  unsigned short* rwkv = (unsigned short*)(ws + 41955328);    // 33,554,432 B (no alias with xb)

  prep_all<<<1024 + MM * DD / 4 / 256, 256, 0, stream>>>(
      Wk, Wv, Wr, Wo, tmk, tmv, tmr, last_x, (const float4*)x,
      wz, wo, bias, (ushort4*)xb, (float4*)out_xlast);

  // Fused: kvr GEMM + WKV -> rwkv [16384, 1024], plus num/den state rows
  gemm_kvr<<<dim3(DD / 64, MM / 128), 256, 0, stream>>>(
      xb, wz, bias, time_first, time_decay, last_num, last_den,
      rwkv, out_num, out_den);

  // out = rwkv @ wo^T : [16384, 1024] — 8-phase 256^2 template
  gemm_bt256<<<dim3(DD / 256, MM / 256), 512, 0, stream>>>(
      rwkv, wo, out, MM, DD, DD);
}